// Round 1
// baseline (376.587 us; speedup 1.0000x reference)
//
#include <hip/hip_runtime.h>
#include <stdint.h>

typedef __bf16 bf16;
typedef __bf16 bf16x8 __attribute__((ext_vector_type(8)));
typedef float f32x4 __attribute__((ext_vector_type(4)));

#define NSEQ 1032
#define BATCH 8
#define NHEADS 12
#define HD 64
#define CDIM 768
#define MROWS (BATCH * NSEQ)   // 8256
#define PREFIX 8

__device__ __forceinline__ unsigned short f2bf_rne(float f) {
    union { float f; uint32_t u; } v; v.f = f;
    uint32_t u = v.u;
    return (unsigned short)((u + 0x7fffu + ((u >> 16) & 1u)) >> 16);
}

__global__ void cast_kernel(const float* __restrict__ src, bf16* __restrict__ dst, int n4) {
    int i = blockIdx.x * blockDim.x + threadIdx.x;
    if (i < n4) {
        float4 f = ((const float4*)src)[i];
        ushort4 o;
        o.x = f2bf_rne(f.x); o.y = f2bf_rne(f.y);
        o.z = f2bf_rne(f.z); o.w = f2bf_rne(f.w);
        ((ushort4*)dst)[i] = o;
    }
}

// NT GEMM: C[m,n] = sum_k A[m,k]*B[n,k] + bias[n]
// EPI=0: write fp32 to Cout[M][N].
// EPI=1: qkv k/v epilogue: n<768 -> K buffer [B,H,N,64]; n>=768 -> V^T buffer [B,H,64,N]
template<int EPI>
__global__ __launch_bounds__(256) void gemm_nt(
    const bf16* __restrict__ A, const bf16* __restrict__ B,
    const float* __restrict__ bias,
    float* __restrict__ Cout, bf16* __restrict__ Kout, bf16* __restrict__ VTout,
    int M, int N, int K)
{
    __shared__ bf16 sA[128][40];
    __shared__ bf16 sB[128][40];
    const int t = threadIdx.x;
    const int w = t >> 6;
    const int l = t & 63;
    const int quad = l >> 4;
    const int l15 = l & 15;
    const int wy = w >> 1, wx = w & 1;
    const int m0 = blockIdx.y * 128;
    const int n0 = blockIdx.x * 128;

    f32x4 acc[4][4] = {};

    for (int k0 = 0; k0 < K; k0 += 32) {
        __syncthreads();
        #pragma unroll
        for (int p = 0; p < 2; ++p) {
            int idx = p * 256 + t;
            int row = idx >> 2;
            int ck  = (idx & 3) * 8;
            int ra = m0 + row; if (ra >= M) ra = M - 1;
            *(uint4*)&sA[row][ck] = *(const uint4*)&A[(size_t)ra * K + k0 + ck];
            int rb = n0 + row;   // N assumed multiple of 128
            *(uint4*)&sB[row][ck] = *(const uint4*)&B[(size_t)rb * K + k0 + ck];
        }
        __syncthreads();
        bf16x8 af[4], bq[4];
        #pragma unroll
        for (int mt = 0; mt < 4; ++mt)
            af[mt] = *(const bf16x8*)&sA[wy*64 + mt*16 + l15][quad*8];
        #pragma unroll
        for (int nt = 0; nt < 4; ++nt)
            bq[nt] = *(const bf16x8*)&sB[wx*64 + nt*16 + l15][quad*8];
        #pragma unroll
        for (int mt = 0; mt < 4; ++mt)
            #pragma unroll
            for (int nt = 0; nt < 4; ++nt)
                acc[mt][nt] = __builtin_amdgcn_mfma_f32_16x16x32_bf16(af[mt], bq[nt], acc[mt][nt], 0, 0, 0);
    }

    #pragma unroll
    for (int mt = 0; mt < 4; ++mt) {
        #pragma unroll
        for (int r = 0; r < 4; ++r) {
            int m = m0 + wy*64 + mt*16 + quad*4 + r;
            if (m >= M) continue;
            #pragma unroll
            for (int nt = 0; nt < 4; ++nt) {
                int n = n0 + wx*64 + nt*16 + l15;
                float v = acc[mt][nt][r] + bias[n];
                if (EPI == 0) {
                    Cout[(size_t)m * N + n] = v;
                } else {
                    int b = m / NSEQ, s = m % NSEQ;
                    if (n < CDIM) {
                        int h = n >> 6, d = n & 63;
                        Kout[(((size_t)(b*NHEADS + h))*NSEQ + s)*HD + d] = (bf16)v;
                    } else {
                        int n2 = n - CDIM;
                        int h = n2 >> 6, d = n2 & 63;
                        VTout[(((size_t)(b*NHEADS + h))*HD + d)*NSEQ + s] = (bf16)v;
                    }
                }
            }
        }
    }
}

// Flash-style attention: S = K K^T * 0.125 + add, softmax, O = S V.
// Q-tile 128 rows, K-tile 64 cols. Per-wave: 32 rows.
__global__ __launch_bounds__(256) void attn_kernel(
    const bf16* __restrict__ Kbuf, const bf16* __restrict__ VTbuf,
    bf16* __restrict__ Hout)
{
    const int bh = blockIdx.y;
    const int b = bh / NHEADS, h = bh % NHEADS;
    const int q0 = blockIdx.x * 128;
    const bf16* Kh  = Kbuf  + (size_t)bh * NSEQ * HD;
    const bf16* VTh = VTbuf + (size_t)bh * HD * NSEQ;

    __shared__ bf16 sQ[128][72];
    __shared__ bf16 sK[64][72];
    __shared__ bf16 sVT[64][72];
    __shared__ bf16 sP[128][72];

    const int t = threadIdx.x;
    const int w = t >> 6, l = t & 63, quad = l >> 4, l15 = l & 15;

    // stage Q tile (rows = this tile's query rows, from K buffer since q := k)
    #pragma unroll
    for (int p = 0; p < 4; ++p) {
        int idx = p * 256 + t;       // 0..1023
        int row = idx >> 3;          // 0..127
        int ck  = (idx & 7) * 8;     // 0..56
        int rg = q0 + row; if (rg >= NSEQ) rg = NSEQ - 1;
        *(uint4*)&sQ[row][ck] = *(const uint4*)&Kh[(size_t)rg * HD + ck];
    }

    f32x4 Oacc[2][4] = {};
    float mrow[2][4], lrow[2][4];
    #pragma unroll
    for (int mt = 0; mt < 2; ++mt)
        #pragma unroll
        for (int r = 0; r < 4; ++r) { mrow[mt][r] = -1e30f; lrow[mt][r] = 0.f; }

    const float scale = 0.125f;   // 64^-0.5
    const float cc2 = 0.02f;      // 1/(2*std^2)

    for (int j0 = 0; j0 < NSEQ; j0 += 64) {
        __syncthreads();
        // stage K-tile [64][64] and VT-tile [64][64]
        #pragma unroll
        for (int p = 0; p < 2; ++p) {
            int id2 = p * 256 + t;   // 0..511
            int row = id2 >> 3;      // 0..63
            int ck  = (id2 & 7) * 8; // 0..56
            int rg = j0 + row; if (rg >= NSEQ) rg = NSEQ - 1;
            *(uint4*)&sK[row][ck] = *(const uint4*)&Kh[(size_t)rg * HD + ck];
            if (j0 + ck + 8 <= NSEQ) {
                *(uint4*)&sVT[row][ck] = *(const uint4*)&VTh[(size_t)row * NSEQ + j0 + ck];
            } else {
                for (int e = 0; e < 8; ++e) {
                    int jj = j0 + ck + e;
                    sVT[row][ck + e] = (jj < NSEQ) ? VTh[(size_t)row * NSEQ + jj] : (bf16)0.f;
                }
            }
        }
        __syncthreads();

        // S = Q K^T for this wave's 32 rows x 64 cols
        f32x4 sacc[2][4] = {};
        #pragma unroll
        for (int ks = 0; ks < 2; ++ks) {
            bf16x8 af[2], bq[4];
            #pragma unroll
            for (int mt = 0; mt < 2; ++mt)
                af[mt] = *(const bf16x8*)&sQ[w*32 + mt*16 + l15][ks*32 + quad*8];
            #pragma unroll
            for (int nt = 0; nt < 4; ++nt)
                bq[nt] = *(const bf16x8*)&sK[nt*16 + l15][ks*32 + quad*8];
            #pragma unroll
            for (int mt = 0; mt < 2; ++mt)
                #pragma unroll
                for (int nt = 0; nt < 4; ++nt)
                    sacc[mt][nt] = __builtin_amdgcn_mfma_f32_16x16x32_bf16(af[mt], bq[nt], sacc[mt][nt], 0, 0, 0);
        }

        // scale + Gaussian additive bias + mask
        #pragma unroll
        for (int mt = 0; mt < 2; ++mt) {
            int rowbase = q0 + w*32 + mt*16 + quad*4;
            #pragma unroll
            for (int nt = 0; nt < 4; ++nt) {
                int col = j0 + nt*16 + l15;
                bool colv = col < NSEQ;
                int cq = col - PREFIX;
                int cl1 = cq >> 5, cl2 = cq & 31;
                #pragma unroll
                for (int r = 0; r < 4; ++r) {
                    int rowg = rowbase + r;
                    float s = sacc[mt][nt][r] * scale;
                    if (rowg >= PREFIX && cq >= 0 && colv) {
                        int p = rowg - PREFIX;
                        int i1 = p >> 5, i2 = p & 31;
                        int d1 = i1 - cl1, d2 = i2 - cl2;
                        s += __expf(-cc2 * (float)(d1*d1 + d2*d2));
                    }
                    if (!colv) s = -1e30f;
                    sacc[mt][nt][r] = s;
                }
            }
        }

        // online softmax update
        #pragma unroll
        for (int mt = 0; mt < 2; ++mt) {
            #pragma unroll
            for (int r = 0; r < 4; ++r) {
                float mx = -1e30f;
                #pragma unroll
                for (int nt = 0; nt < 4; ++nt) mx = fmaxf(mx, sacc[mt][nt][r]);
                #pragma unroll
                for (int msk = 1; msk < 16; msk <<= 1) mx = fmaxf(mx, __shfl_xor(mx, msk, 64));
                float mnew = fmaxf(mrow[mt][r], mx);
                float alpha = __expf(mrow[mt][r] - mnew);
                float rs = 0.f;
                #pragma unroll
                for (int nt = 0; nt < 4; ++nt) {
                    float pv = __expf(sacc[mt][nt][r] - mnew);
                    sacc[mt][nt][r] = pv;
                    rs += pv;
                }
                #pragma unroll
                for (int msk = 1; msk < 16; msk <<= 1) rs += __shfl_xor(rs, msk, 64);
                lrow[mt][r] = lrow[mt][r] * alpha + rs;
                mrow[mt][r] = mnew;
                #pragma unroll
                for (int nt = 0; nt < 4; ++nt) Oacc[mt][nt] [r] *= alpha;
            }
        }

        // P -> LDS (C-layout to A-layout round trip), per-wave private rows
        #pragma unroll
        for (int mt = 0; mt < 2; ++mt)
            #pragma unroll
            for (int nt = 0; nt < 4; ++nt)
                #pragma unroll
                for (int r = 0; r < 4; ++r)
                    sP[w*32 + mt*16 + quad*4 + r][nt*16 + l15] = (bf16)sacc[mt][nt][r];
        __syncthreads();

        // O += P V  (contract over j: K=64 -> 2 k-steps)
        #pragma unroll
        for (int ks = 0; ks < 2; ++ks) {
            bf16x8 af[2], bq[4];
            #pragma unroll
            for (int mt = 0; mt < 2; ++mt)
                af[mt] = *(const bf16x8*)&sP[w*32 + mt*16 + l15][ks*32 + quad*8];
            #pragma unroll
            for (int nt = 0; nt < 4; ++nt)
                bq[nt] = *(const bf16x8*)&sVT[nt*16 + l15][ks*32 + quad*8];
            #pragma unroll
            for (int mt = 0; mt < 2; ++mt)
                #pragma unroll
                for (int nt = 0; nt < 4; ++nt)
                    Oacc[mt][nt] = __builtin_amdgcn_mfma_f32_16x16x32_bf16(af[mt], bq[nt], Oacc[mt][nt], 0, 0, 0);
        }
    }

    // write O / l  to hidden [MROWS][CDIM] bf16
    #pragma unroll
    for (int mt = 0; mt < 2; ++mt) {
        #pragma unroll
        for (int r = 0; r < 4; ++r) {
            int rowg = q0 + w*32 + mt*16 + quad*4 + r;
            if (rowg >= NSEQ) continue;
            float inv = 1.f / lrow[mt][r];
            size_t base = ((size_t)(b * NSEQ) + rowg) * CDIM + h * HD;
            #pragma unroll
            for (int nt = 0; nt < 4; ++nt)
                Hout[base + nt*16 + l15] = (bf16)(Oacc[mt][nt][r] * inv);
        }
    }
}

extern "C" void kernel_launch(void* const* d_in, const int* in_sizes, int n_in,
                              void* d_out, int out_size, void* d_ws, size_t ws_size,
                              hipStream_t stream) {
    const float* x      = (const float*)d_in[0];
    const float* qkv_w  = (const float*)d_in[1];
    const float* qkv_b  = (const float*)d_in[2];
    const float* proj_w = (const float*)d_in[3];
    const float* proj_b = (const float*)d_in[4];
    float* out = (float*)d_out;

    char* ws = (char*)d_ws;
    const size_t XBF_BYTES   = (size_t)MROWS * CDIM * 2;          // 12,681,216 (also hidden)
    const size_t WKV_BYTES   = (size_t)2 * CDIM * CDIM * 2;       // 2,359,296
    const size_t PW_BYTES    = (size_t)CDIM * CDIM * 2;           // 1,179,648
    const size_t KBF_BYTES   = (size_t)BATCH * NHEADS * NSEQ * HD * 2;

    bf16* x_bf   = (bf16*)ws;                                     // later reused as hidden
    bf16* wkv_bf = (bf16*)(ws + XBF_BYTES);
    bf16* pw_bf  = (bf16*)(ws + XBF_BYTES + WKV_BYTES);
    bf16* k_bf   = (bf16*)(ws + XBF_BYTES + WKV_BYTES + PW_BYTES);
    bf16* vT_bf  = (bf16*)(ws + XBF_BYTES + WKV_BYTES + PW_BYTES + KBF_BYTES);

    // casts
    {
        int n4 = MROWS * CDIM / 4;
        cast_kernel<<<dim3((n4 + 255) / 256), dim3(256), 0, stream>>>(x, x_bf, n4);
    }
    {
        int n4 = 2 * CDIM * CDIM / 4;
        cast_kernel<<<dim3((n4 + 255) / 256), dim3(256), 0, stream>>>(qkv_w + (size_t)CDIM * CDIM, wkv_bf, n4);
    }
    {
        int n4 = CDIM * CDIM / 4;
        cast_kernel<<<dim3((n4 + 255) / 256), dim3(256), 0, stream>>>(proj_w, pw_bf, n4);
    }

    // qkv GEMM (k & v only): M=8256, N=1536, K=768
    {
        dim3 grid(1536 / 128, (MROWS + 127) / 128);
        gemm_nt<1><<<grid, dim3(256), 0, stream>>>(x_bf, wkv_bf, qkv_b + CDIM,
                                                   nullptr, k_bf, vT_bf,
                                                   MROWS, 1536, CDIM);
    }

    // attention -> hidden (reuse x_bf buffer)
    {
        dim3 grid((NSEQ + 127) / 128, BATCH * NHEADS);
        attn_kernel<<<grid, dim3(256), 0, stream>>>(k_bf, vT_bf, x_bf);
    }

    // proj GEMM: out = hidden @ proj_w^T + proj_b, fp32 out
    {
        dim3 grid(CDIM / 128, (MROWS + 127) / 128);
        gemm_nt<0><<<grid, dim3(256), 0, stream>>>(x_bf, pw_bf, proj_b,
                                                   out, nullptr, nullptr,
                                                   MROWS, CDIM, CDIM);
    }
}

// Round 2
// 296.194 us; speedup vs baseline: 1.2714x; 1.2714x over previous
//
#include <hip/hip_runtime.h>
#include <stdint.h>

typedef __bf16 bf16;
typedef __bf16 bf16x8 __attribute__((ext_vector_type(8)));
typedef __bf16 bf16x4 __attribute__((ext_vector_type(4)));
typedef float f32x4 __attribute__((ext_vector_type(4)));

#define NSEQ 1032
#define BATCH 8
#define NHEADS 12
#define HD 64
#define CDIM 768
#define MROWS (BATCH * NSEQ)   // 8256
#define PREFIX 8
#define BQ_ROWS 1152           // padded query rows for bias table (9*128)
#define BK_COLS 1088           // padded key cols for bias table (17*64)

__device__ __forceinline__ unsigned short f2bf_rne(float f) {
    union { float f; uint32_t u; } v; v.f = f;
    uint32_t u = v.u;
    return (unsigned short)((u + 0x7fffu + ((u >> 16) & 1u)) >> 16);
}

__global__ void cast_kernel(const float* __restrict__ src, bf16* __restrict__ dst, int n4) {
    int i = blockIdx.x * blockDim.x + threadIdx.x;
    if (i < n4) {
        float4 f = ((const float4*)src)[i];
        ushort4 o;
        o.x = f2bf_rne(f.x); o.y = f2bf_rne(f.y);
        o.z = f2bf_rne(f.z); o.w = f2bf_rne(f.w);
        ((ushort4*)dst)[i] = o;
    }
}

// Bias table: Bias8[q][k] = 8 * gauss(q,k) for valid, 0 for prefix/pad rows,
// -1e30 for invalid key columns (tail mask). Layout [1152][1088] fp32.
__global__ void bias_kernel(float* __restrict__ Bias8) {
    int i = blockIdx.x * blockDim.x + threadIdx.x;
    if (i >= BQ_ROWS * BK_COLS) return;
    int q = i / BK_COLS, k = i % BK_COLS;
    float v;
    if (k >= NSEQ) v = -1e30f;
    else if (q < PREFIX || q >= NSEQ || k < PREFIX) v = 0.f;
    else {
        int rp = q - PREFIX, cp = k - PREFIX;
        int d1 = (rp >> 5) - (cp >> 5);
        int d2 = (rp & 31) - (cp & 31);
        v = 8.f * __expf(-0.02f * (float)(d1 * d1 + d2 * d2));
    }
    Bias8[i] = v;
}

// NT GEMM: C[m,n] = sum_k A[m,k]*B[n,k] + bias[n]
// EPI=0: write fp32 to Cout[M][N].
// EPI=1: qkv k/v epilogue: n<768 -> K buffer [B,H,N,64]; n>=768 -> V^T buffer [B,H,64,N]
template<int EPI>
__global__ __launch_bounds__(256) void gemm_nt(
    const bf16* __restrict__ A, const bf16* __restrict__ B,
    const float* __restrict__ bias,
    float* __restrict__ Cout, bf16* __restrict__ Kout, bf16* __restrict__ VTout,
    int M, int N, int K)
{
    __shared__ bf16 sA[128][40];
    __shared__ bf16 sB[128][40];
    const int t = threadIdx.x;
    const int w = t >> 6;
    const int l = t & 63;
    const int quad = l >> 4;
    const int l15 = l & 15;
    const int wy = w >> 1, wx = w & 1;
    const int m0 = blockIdx.y * 128;
    const int n0 = blockIdx.x * 128;

    f32x4 acc[4][4] = {};

    for (int k0 = 0; k0 < K; k0 += 32) {
        __syncthreads();
        #pragma unroll
        for (int p = 0; p < 2; ++p) {
            int idx = p * 256 + t;
            int row = idx >> 2;
            int ck  = (idx & 3) * 8;
            int ra = m0 + row; if (ra >= M) ra = M - 1;
            *(uint4*)&sA[row][ck] = *(const uint4*)&A[(size_t)ra * K + k0 + ck];
            int rb = n0 + row;   // N assumed multiple of 128
            *(uint4*)&sB[row][ck] = *(const uint4*)&B[(size_t)rb * K + k0 + ck];
        }
        __syncthreads();
        bf16x8 af[4], bq[4];
        #pragma unroll
        for (int mt = 0; mt < 4; ++mt)
            af[mt] = *(const bf16x8*)&sA[wy*64 + mt*16 + l15][quad*8];
        #pragma unroll
        for (int nt = 0; nt < 4; ++nt)
            bq[nt] = *(const bf16x8*)&sB[wx*64 + nt*16 + l15][quad*8];
        #pragma unroll
        for (int mt = 0; mt < 4; ++mt)
            #pragma unroll
            for (int nt = 0; nt < 4; ++nt)
                acc[mt][nt] = __builtin_amdgcn_mfma_f32_16x16x32_bf16(af[mt], bq[nt], acc[mt][nt], 0, 0, 0);
    }

    #pragma unroll
    for (int mt = 0; mt < 4; ++mt) {
        #pragma unroll
        for (int r = 0; r < 4; ++r) {
            int m = m0 + wy*64 + mt*16 + quad*4 + r;
            if (m >= M) continue;
            #pragma unroll
            for (int nt = 0; nt < 4; ++nt) {
                int n = n0 + wx*64 + nt*16 + l15;
                float v = acc[mt][nt][r] + bias[n];
                if (EPI == 0) {
                    Cout[(size_t)m * N + n] = v;
                } else {
                    int b = m / NSEQ, s = m % NSEQ;
                    if (n < CDIM) {
                        int h = n >> 6, d = n & 63;
                        Kout[(((size_t)(b*NHEADS + h))*NSEQ + s)*HD + d] = (bf16)v;
                    } else {
                        int n2 = n - CDIM;
                        int h = n2 >> 6, d = n2 & 63;
                        VTout[(((size_t)(b*NHEADS + h))*HD + d)*NSEQ + s] = (bf16)v;
                    }
                }
            }
        }
    }
}

// Attention: S = K K^T * 0.125 + add  (add preloaded via MFMA C init, x8),
// no-max softmax (logits bounded), O = P V / rowsum.
// Q-tile 128 (4 waves x 32 rows), K-tile 64. S computed TRANSPOSED
// (A = K-tile, B = Q-frag) so P lands query=col -> packed b64 sP stores.
__global__ __launch_bounds__(256, 4) void attn_kernel(
    const bf16* __restrict__ Kbuf, const bf16* __restrict__ VTbuf,
    const float* __restrict__ Bias8, bf16* __restrict__ Hout)
{
    const int bh = blockIdx.y;
    const int b = bh / NHEADS, h = bh % NHEADS;
    const int q0 = blockIdx.x * 128;
    const bf16* Kh  = Kbuf  + (size_t)bh * NSEQ * HD;
    const bf16* VTh = VTbuf + (size_t)bh * HD * NSEQ;

    __shared__ bf16 sK[64][72];
    __shared__ bf16 sVT[64][72];
    __shared__ bf16 sP[128][72];
    __shared__ float sL[128];

    const int t = threadIdx.x;
    const int w = t >> 6, l = t & 63, quad = l >> 4, l15 = l & 15;

    // Q fragments in registers (B-operand: B[k=d][n=query], contiguous in Q row)
    bf16x8 qf[2][2];
    #pragma unroll
    for (int mt = 0; mt < 2; ++mt) {
        int row = q0 + w*32 + mt*16 + l15;
        if (row > NSEQ - 1) row = NSEQ - 1;
        #pragma unroll
        for (int ks = 0; ks < 2; ++ks)
            qf[mt][ks] = *(const bf16x8*)&Kh[(size_t)row * HD + ks*32 + quad*8];
    }

    f32x4 Oacc[2][4] = {};
    float psum[2] = {0.f, 0.f};
    const float scale = 0.125f;

    for (int j0 = 0; j0 < NSEQ; j0 += 64) {
        __syncthreads();
        // stage K-tile [64][64] and VT-tile [64][64]
        #pragma unroll
        for (int p = 0; p < 2; ++p) {
            int id2 = p * 256 + t;   // 0..511
            int row = id2 >> 3;      // 0..63
            int ck  = (id2 & 7) * 8; // 0..56
            int rk = j0 + row; if (rk > NSEQ - 1) rk = NSEQ - 1;
            *(uint4*)&sK[row][ck] = *(const uint4*)&Kh[(size_t)rk * HD + ck];
            int cs = j0 + ck; if (cs > NSEQ - 8) cs = NSEQ - 8;  // tail cols masked by bias
            *(uint4*)&sVT[row][ck] = *(const uint4*)&VTh[(size_t)row * NSEQ + cs];
        }
        __syncthreads();

        // init accumulators with bias*8 (C-layout: row=key, col=query)
        f32x4 sacc[4][2];
        #pragma unroll
        for (int kt = 0; kt < 4; ++kt) {
            #pragma unroll
            for (int mt = 0; mt < 2; ++mt) {
                int qg = q0 + w*32 + mt*16 + l15;     // < 1152, in table
                int kg = j0 + kt*16 + quad*4;          // < 1088, in table
                sacc[kt][mt] = *(const f32x4*)&Bias8[(size_t)qg * BK_COLS + kg];
            }
        }

        // S^T = K * Q^T  (A = K rows = keys, B = Q rows = queries)
        #pragma unroll
        for (int ks = 0; ks < 2; ++ks) {
            bf16x8 af[4];
            #pragma unroll
            for (int kt = 0; kt < 4; ++kt)
                af[kt] = *(const bf16x8*)&sK[kt*16 + l15][ks*32 + quad*8];
            #pragma unroll
            for (int kt = 0; kt < 4; ++kt)
                #pragma unroll
                for (int mt = 0; mt < 2; ++mt)
                    sacc[kt][mt] = __builtin_amdgcn_mfma_f32_16x16x32_bf16(af[kt], qf[mt][ks], sacc[kt][mt], 0, 0, 0);
        }

        // P = exp(scale * (KK^T + bias*8)); packed b64 store (4 keys/lane)
        #pragma unroll
        for (int kt = 0; kt < 4; ++kt) {
            #pragma unroll
            for (int mt = 0; mt < 2; ++mt) {
                float p0 = __expf(sacc[kt][mt][0] * scale);
                float p1 = __expf(sacc[kt][mt][1] * scale);
                float p2 = __expf(sacc[kt][mt][2] * scale);
                float p3 = __expf(sacc[kt][mt][3] * scale);
                psum[mt] += (p0 + p1) + (p2 + p3);
                bf16x4 pv = { (bf16)p0, (bf16)p1, (bf16)p2, (bf16)p3 };
                *(bf16x4*)&sP[w*32 + mt*16 + l15][kt*16 + quad*4] = pv;
            }
        }

        // O += P V   (sP is wave-private rows; sVT synced above -> no barrier)
        #pragma unroll
        for (int ks = 0; ks < 2; ++ks) {
            bf16x8 ap[2], bv[4];
            #pragma unroll
            for (int mt = 0; mt < 2; ++mt)
                ap[mt] = *(const bf16x8*)&sP[w*32 + mt*16 + l15][ks*32 + quad*8];
            #pragma unroll
            for (int dt = 0; dt < 4; ++dt)
                bv[dt] = *(const bf16x8*)&sVT[dt*16 + l15][ks*32 + quad*8];
            #pragma unroll
            for (int mt = 0; mt < 2; ++mt)
                #pragma unroll
                for (int dt = 0; dt < 4; ++dt)
                    Oacc[mt][dt] = __builtin_amdgcn_mfma_f32_16x16x32_bf16(ap[mt], bv[dt], Oacc[mt][dt], 0, 0, 0);
        }
    }

    // row sums: reduce across quads (cols are spread over quad), distribute via LDS
    #pragma unroll
    for (int mt = 0; mt < 2; ++mt) {
        float s = psum[mt];
        s += __shfl_xor(s, 16, 64);
        s += __shfl_xor(s, 32, 64);
        if (l < 16) sL[w*32 + mt*16 + l] = s;
    }
    __syncthreads();

    #pragma unroll
    for (int mt = 0; mt < 2; ++mt) {
        #pragma unroll
        for (int r = 0; r < 4; ++r) {
            int g = q0 + w*32 + mt*16 + quad*4 + r;
            if (g >= NSEQ) continue;
            float inv = 1.f / sL[w*32 + mt*16 + quad*4 + r];
            size_t base = ((size_t)(b * NSEQ) + g) * CDIM + h * HD;
            #pragma unroll
            for (int dt = 0; dt < 4; ++dt)
                Hout[base + dt*16 + l15] = (bf16)(Oacc[mt][dt][r] * inv);
        }
    }
}

extern "C" void kernel_launch(void* const* d_in, const int* in_sizes, int n_in,
                              void* d_out, int out_size, void* d_ws, size_t ws_size,
                              hipStream_t stream) {
    const float* x      = (const float*)d_in[0];
    const float* qkv_w  = (const float*)d_in[1];
    const float* qkv_b  = (const float*)d_in[2];
    const float* proj_w = (const float*)d_in[3];
    const float* proj_b = (const float*)d_in[4];
    float* out = (float*)d_out;

    char* ws = (char*)d_ws;
    const size_t XBF_BYTES   = (size_t)MROWS * CDIM * 2;          // 12,681,216 (also hidden)
    const size_t WKV_BYTES   = (size_t)2 * CDIM * CDIM * 2;       // 2,359,296
    const size_t PW_BYTES    = (size_t)CDIM * CDIM * 2;           // 1,179,648
    const size_t KBF_BYTES   = (size_t)BATCH * NHEADS * NSEQ * HD * 2;

    bf16* x_bf   = (bf16*)ws;                                     // later reused as hidden
    bf16* wkv_bf = (bf16*)(ws + XBF_BYTES);
    bf16* pw_bf  = (bf16*)(ws + XBF_BYTES + WKV_BYTES);
    bf16* k_bf   = (bf16*)(ws + XBF_BYTES + WKV_BYTES + PW_BYTES);
    bf16* vT_bf  = (bf16*)(ws + XBF_BYTES + WKV_BYTES + PW_BYTES + KBF_BYTES);
    float* bias8 = (float*)(ws + XBF_BYTES + WKV_BYTES + PW_BYTES + KBF_BYTES + KBF_BYTES);

    // bias table (independent of inputs; recomputed every call)
    {
        int n = BQ_ROWS * BK_COLS;
        bias_kernel<<<dim3((n + 255) / 256), dim3(256), 0, stream>>>(bias8);
    }

    // casts
    {
        int n4 = MROWS * CDIM / 4;
        cast_kernel<<<dim3((n4 + 255) / 256), dim3(256), 0, stream>>>(x, x_bf, n4);
    }
    {
        int n4 = 2 * CDIM * CDIM / 4;
        cast_kernel<<<dim3((n4 + 255) / 256), dim3(256), 0, stream>>>(qkv_w + (size_t)CDIM * CDIM, wkv_bf, n4);
    }
    {
        int n4 = CDIM * CDIM / 4;
        cast_kernel<<<dim3((n4 + 255) / 256), dim3(256), 0, stream>>>(proj_w, pw_bf, n4);
    }

    // qkv GEMM (k & v only): M=8256, N=1536, K=768
    {
        dim3 grid(1536 / 128, (MROWS + 127) / 128);
        gemm_nt<1><<<grid, dim3(256), 0, stream>>>(x_bf, wkv_bf, qkv_b + CDIM,
                                                   nullptr, k_bf, vT_bf,
                                                   MROWS, 1536, CDIM);
    }

    // attention -> hidden (reuse x_bf buffer)
    {
        dim3 grid((NSEQ + 127) / 128, BATCH * NHEADS);
        attn_kernel<<<grid, dim3(256), 0, stream>>>(k_bf, vT_bf, bias8, x_bf);
    }

    // proj GEMM: out = hidden @ proj_w^T + proj_b, fp32 out
    {
        dim3 grid(CDIM / 128, (MROWS + 127) / 128);
        gemm_nt<0><<<grid, dim3(256), 0, stream>>>(x_bf, pw_bf, proj_b,
                                                   out, nullptr, nullptr,
                                                   MROWS, CDIM, CDIM);
    }
}

// Round 3
// 288.781 us; speedup vs baseline: 1.3041x; 1.0257x over previous
//
#include <hip/hip_runtime.h>
#include <stdint.h>

typedef __bf16 bf16;
typedef __bf16 bf16x8 __attribute__((ext_vector_type(8)));
typedef __bf16 bf16x4 __attribute__((ext_vector_type(4)));
typedef float f32x4 __attribute__((ext_vector_type(4)));

#define NSEQ 1032
#define BATCH 8
#define NHEADS 12
#define HD 64
#define CDIM 768
#define MROWS (BATCH * NSEQ)   // 8256
#define PREFIX 8
#define BQ_ROWS 1152           // padded query rows for bias table (9*128)
#define BK_COLS 1088           // padded key cols for bias table (17*64)

__device__ __forceinline__ unsigned short f2bf_rne(float f) {
    union { float f; uint32_t u; } v; v.f = f;
    uint32_t u = v.u;
    return (unsigned short)((u + 0x7fffu + ((u >> 16) & 1u)) >> 16);
}

__device__ __forceinline__ void gload_lds16(const bf16* g, bf16* l) {
    __builtin_amdgcn_global_load_lds(
        (const __attribute__((address_space(1))) void*)g,
        (__attribute__((address_space(3))) void*)l, 16, 0, 0);
}

__global__ void cast_kernel(const float* __restrict__ src, bf16* __restrict__ dst, int n4) {
    int i = blockIdx.x * blockDim.x + threadIdx.x;
    if (i < n4) {
        float4 f = ((const float4*)src)[i];
        ushort4 o;
        o.x = f2bf_rne(f.x); o.y = f2bf_rne(f.y);
        o.z = f2bf_rne(f.z); o.w = f2bf_rne(f.w);
        ((ushort4*)dst)[i] = o;
    }
}

// Bias table: Bias8[q][k] = 8 * gauss(q,k) for valid, 0 for prefix/pad rows,
// -1e30 for invalid key columns (tail mask). Layout [1152][1088] fp32.
__global__ void bias_kernel(float* __restrict__ Bias8) {
    int i = blockIdx.x * blockDim.x + threadIdx.x;
    if (i >= BQ_ROWS * BK_COLS) return;
    int q = i / BK_COLS, k = i % BK_COLS;
    float v;
    if (k >= NSEQ) v = -1e30f;
    else if (q < PREFIX || q >= NSEQ || k < PREFIX) v = 0.f;
    else {
        int rp = q - PREFIX, cp = k - PREFIX;
        int d1 = (rp >> 5) - (cp >> 5);
        int d2 = (rp & 31) - (cp & 31);
        v = 8.f * __expf(-0.02f * (float)(d1 * d1 + d2 * d2));
    }
    Bias8[i] = v;
}

// NT GEMM, m97-style: global_load_lds width-16 staging into unpadded 128x32
// tiles with XOR-swizzled 16B chunks (chunk = quad ^ ((row>>1)&3)).
// EPI=0: write fp32 to Cout[M][N].
// EPI=1: qkv k/v epilogue: n<768 -> K buffer [B,H,N,64]; n>=768 -> V^T [B,H,64,N]
template<int EPI>
__global__ __launch_bounds__(256) void gemm_nt(
    const bf16* __restrict__ A, const bf16* __restrict__ B,
    const float* __restrict__ bias,
    float* __restrict__ Cout, bf16* __restrict__ Kout, bf16* __restrict__ VTout,
    int M, int N, int K)
{
    __shared__ bf16 sA[128 * 32];
    __shared__ bf16 sB[128 * 32];
    const int t = threadIdx.x;
    const int w = t >> 6;
    const int l = t & 63;
    const int quad = l >> 4;
    const int l15 = l & 15;
    const int wy = w >> 1, wx = w & 1;
    const int m0 = blockIdx.y * 128;
    const int n0 = blockIdx.x * 128;
    const int co = (quad ^ ((l15 >> 1) & 3)) * 8;   // swizzled k-chunk offset (bf16)

    f32x4 acc[4][4] = {};

    for (int k0 = 0; k0 < K; k0 += 32) {
        __syncthreads();
        #pragma unroll
        for (int p = 0; p < 2; ++p) {
            int ci = p * 256 + t;
            int row = ci >> 2;
            int c = (ci & 3) ^ ((row >> 1) & 3);
            int ra = m0 + row; if (ra >= M) ra = M - 1;
            int rb = n0 + row;                     // N multiple of 128
            bf16* dst = &sA[(size_t)(p * 256 + w * 64) * 8];
            gload_lds16(&A[(size_t)ra * K + k0 + c * 8], dst);
            bf16* dstB = &sB[(size_t)(p * 256 + w * 64) * 8];
            gload_lds16(&B[(size_t)rb * K + k0 + c * 8], dstB);
        }
        __syncthreads();
        bf16x8 af[4], bq[4];
        #pragma unroll
        for (int mt = 0; mt < 4; ++mt)
            af[mt] = *(const bf16x8*)&sA[(wy*64 + mt*16 + l15) * 32 + co];
        #pragma unroll
        for (int nt = 0; nt < 4; ++nt)
            bq[nt] = *(const bf16x8*)&sB[(wx*64 + nt*16 + l15) * 32 + co];
        #pragma unroll
        for (int mt = 0; mt < 4; ++mt)
            #pragma unroll
            for (int nt = 0; nt < 4; ++nt)
                acc[mt][nt] = __builtin_amdgcn_mfma_f32_16x16x32_bf16(af[mt], bq[nt], acc[mt][nt], 0, 0, 0);
    }

    #pragma unroll
    for (int mt = 0; mt < 4; ++mt) {
        #pragma unroll
        for (int r = 0; r < 4; ++r) {
            int m = m0 + wy*64 + mt*16 + quad*4 + r;
            if (m >= M) continue;
            #pragma unroll
            for (int nt = 0; nt < 4; ++nt) {
                int n = n0 + wx*64 + nt*16 + l15;
                float v = acc[mt][nt][r] + bias[n];
                if (EPI == 0) {
                    Cout[(size_t)m * N + n] = v;
                } else {
                    int b = m / NSEQ, s = m % NSEQ;
                    if (n < CDIM) {
                        int h = n >> 6, d = n & 63;
                        Kout[(((size_t)(b*NHEADS + h))*NSEQ + s)*HD + d] = (bf16)v;
                    } else {
                        int n2 = n - CDIM;
                        int h = n2 >> 6, d = n2 & 63;
                        VTout[(((size_t)(b*NHEADS + h))*HD + d)*NSEQ + s] = (bf16)v;
                    }
                }
            }
        }
    }
}

// Attention: S^T = K K^T (bias*8 preloaded as MFMA C init), no-max softmax,
// O = P V / rowsum. 8 waves x 16 query rows = 128-row Q-tile, K-tile 64.
__global__ __launch_bounds__(512) void attn_kernel(
    const bf16* __restrict__ Kbuf, const bf16* __restrict__ VTbuf,
    const float* __restrict__ Bias8, bf16* __restrict__ Hout)
{
    const int bh = blockIdx.y;
    const int b = bh / NHEADS, h = bh % NHEADS;
    const int q0 = blockIdx.x * 128;
    const bf16* Kh  = Kbuf  + (size_t)bh * NSEQ * HD;
    const bf16* VTh = VTbuf + (size_t)bh * HD * NSEQ;

    __shared__ bf16 sK[64][72];
    __shared__ bf16 sVT[64][72];
    __shared__ bf16 sP[128][72];
    __shared__ float sL[128];

    const int t = threadIdx.x;
    const int w = t >> 6, l = t & 63, quad = l >> 4, l15 = l & 15;

    // Q fragment in registers (B-operand; 16 query rows per wave)
    bf16x8 qf[2];
    {
        int row = q0 + w*16 + l15;
        if (row > NSEQ - 1) row = NSEQ - 1;
        #pragma unroll
        for (int ks = 0; ks < 2; ++ks)
            qf[ks] = *(const bf16x8*)&Kh[(size_t)row * HD + ks*32 + quad*8];
    }

    f32x4 Oacc[4] = {};
    float psum = 0.f;
    const float scale = 0.125f;

    // this thread's staging coords (one uint4 per buffer)
    const int srow = t >> 3;
    const int sck  = (t & 7) * 8;

    for (int j0 = 0; j0 < NSEQ; j0 += 64) {
        __syncthreads();
        // issue staging loads into registers
        int rk = j0 + srow; if (rk > NSEQ - 1) rk = NSEQ - 1;
        uint4 kv = *(const uint4*)&Kh[(size_t)rk * HD + sck];
        int cs = j0 + sck; if (cs > NSEQ - 8) cs = NSEQ - 8;   // tail masked by bias
        uint4 vv = *(const uint4*)&VTh[(size_t)srow * NSEQ + cs];

        // bias (C-operand init; row=key, col=query) -- overlaps staging latency
        f32x4 sacc[4];
        #pragma unroll
        for (int kt = 0; kt < 4; ++kt) {
            int qg = q0 + w*16 + l15;
            int kg = j0 + kt*16 + quad*4;
            sacc[kt] = *(const f32x4*)&Bias8[(size_t)qg * BK_COLS + kg];
        }

        *(uint4*)&sK[srow][sck] = kv;
        *(uint4*)&sVT[srow][sck] = vv;
        __syncthreads();

        // S^T = K * Q^T   (A = keys from LDS, B = query frag in regs)
        #pragma unroll
        for (int ks = 0; ks < 2; ++ks) {
            bf16x8 af[4];
            #pragma unroll
            for (int kt = 0; kt < 4; ++kt)
                af[kt] = *(const bf16x8*)&sK[kt*16 + l15][ks*32 + quad*8];
            #pragma unroll
            for (int kt = 0; kt < 4; ++kt)
                sacc[kt] = __builtin_amdgcn_mfma_f32_16x16x32_bf16(af[kt], qf[ks], sacc[kt], 0, 0, 0);
        }

        // P = exp(scale * (KK^T + bias*8)); packed b64 store (4 keys/lane)
        #pragma unroll
        for (int kt = 0; kt < 4; ++kt) {
            float p0 = __expf(sacc[kt][0] * scale);
            float p1 = __expf(sacc[kt][1] * scale);
            float p2 = __expf(sacc[kt][2] * scale);
            float p3 = __expf(sacc[kt][3] * scale);
            psum += (p0 + p1) + (p2 + p3);
            bf16x4 pv = { (bf16)p0, (bf16)p1, (bf16)p2, (bf16)p3 };
            *(bf16x4*)&sP[w*16 + l15][kt*16 + quad*4] = pv;
        }

        // O += P V   (sP rows wave-private; sVT covered by barrier above)
        #pragma unroll
        for (int ks = 0; ks < 2; ++ks) {
            bf16x8 ap, bv[4];
            ap = *(const bf16x8*)&sP[w*16 + l15][ks*32 + quad*8];
            #pragma unroll
            for (int dt = 0; dt < 4; ++dt)
                bv[dt] = *(const bf16x8*)&sVT[dt*16 + l15][ks*32 + quad*8];
            #pragma unroll
            for (int dt = 0; dt < 4; ++dt)
                Oacc[dt] = __builtin_amdgcn_mfma_f32_16x16x32_bf16(ap, bv[dt], Oacc[dt], 0, 0, 0);
        }
    }

    // row sums: reduce across quads, distribute via LDS
    {
        float s = psum;
        s += __shfl_xor(s, 16, 64);
        s += __shfl_xor(s, 32, 64);
        if (l < 16) sL[w*16 + l] = s;
    }
    __syncthreads();

    #pragma unroll
    for (int r = 0; r < 4; ++r) {
        int g = q0 + w*16 + quad*4 + r;
        if (g >= NSEQ) continue;
        float inv = 1.f / sL[w*16 + quad*4 + r];
        size_t base = ((size_t)(b * NSEQ) + g) * CDIM + h * HD;
        #pragma unroll
        for (int dt = 0; dt < 4; ++dt)
            Hout[base + dt*16 + l15] = (bf16)(Oacc[dt][r] * inv);
    }
}

extern "C" void kernel_launch(void* const* d_in, const int* in_sizes, int n_in,
                              void* d_out, int out_size, void* d_ws, size_t ws_size,
                              hipStream_t stream) {
    const float* x      = (const float*)d_in[0];
    const float* qkv_w  = (const float*)d_in[1];
    const float* qkv_b  = (const float*)d_in[2];
    const float* proj_w = (const float*)d_in[3];
    const float* proj_b = (const float*)d_in[4];
    float* out = (float*)d_out;

    char* ws = (char*)d_ws;
    const size_t XBF_BYTES   = (size_t)MROWS * CDIM * 2;          // 12,681,216 (also hidden)
    const size_t WKV_BYTES   = (size_t)2 * CDIM * CDIM * 2;       // 2,359,296
    const size_t PW_BYTES    = (size_t)CDIM * CDIM * 2;           // 1,179,648
    const size_t KBF_BYTES   = (size_t)BATCH * NHEADS * NSEQ * HD * 2;

    bf16* x_bf   = (bf16*)ws;                                     // later reused as hidden
    bf16* wkv_bf = (bf16*)(ws + XBF_BYTES);
    bf16* pw_bf  = (bf16*)(ws + XBF_BYTES + WKV_BYTES);
    bf16* k_bf   = (bf16*)(ws + XBF_BYTES + WKV_BYTES + PW_BYTES);
    bf16* vT_bf  = (bf16*)(ws + XBF_BYTES + WKV_BYTES + PW_BYTES + KBF_BYTES);
    float* bias8 = (float*)(ws + XBF_BYTES + WKV_BYTES + PW_BYTES + KBF_BYTES + KBF_BYTES);

    // bias table (independent of inputs; recomputed every call)
    {
        int n = BQ_ROWS * BK_COLS;
        bias_kernel<<<dim3((n + 255) / 256), dim3(256), 0, stream>>>(bias8);
    }

    // casts
    {
        int n4 = MROWS * CDIM / 4;
        cast_kernel<<<dim3((n4 + 255) / 256), dim3(256), 0, stream>>>(x, x_bf, n4);
    }
    {
        int n4 = 2 * CDIM * CDIM / 4;
        cast_kernel<<<dim3((n4 + 255) / 256), dim3(256), 0, stream>>>(qkv_w + (size_t)CDIM * CDIM, wkv_bf, n4);
    }
    {
        int n4 = CDIM * CDIM / 4;
        cast_kernel<<<dim3((n4 + 255) / 256), dim3(256), 0, stream>>>(proj_w, pw_bf, n4);
    }

    // qkv GEMM (k & v only): M=8256, N=1536, K=768
    {
        dim3 grid(1536 / 128, (MROWS + 127) / 128);
        gemm_nt<1><<<grid, dim3(256), 0, stream>>>(x_bf, wkv_bf, qkv_b + CDIM,
                                                   nullptr, k_bf, vT_bf,
                                                   MROWS, 1536, CDIM);
    }

    // attention -> hidden (reuse x_bf buffer)
    {
        dim3 grid((NSEQ + 127) / 128, BATCH * NHEADS);
        attn_kernel<<<grid, dim3(512), 0, stream>>>(k_bf, vT_bf, bias8, x_bf);
    }

    // proj GEMM: out = hidden @ proj_w^T + proj_b, fp32 out
    {
        dim3 grid(CDIM / 128, (MROWS + 127) / 128);
        gemm_nt<0><<<grid, dim3(256), 0, stream>>>(x_bf, pw_bf, proj_b,
                                                   out, nullptr, nullptr,
                                                   MROWS, CDIM, CDIM);
    }
}

// Round 4
// 277.370 us; speedup vs baseline: 1.3577x; 1.0411x over previous
//
#include <hip/hip_runtime.h>
#include <stdint.h>

typedef __bf16 bf16;
typedef __bf16 bf16x8 __attribute__((ext_vector_type(8)));
typedef __bf16 bf16x4 __attribute__((ext_vector_type(4)));
typedef float f32x4 __attribute__((ext_vector_type(4)));

#define NSEQ 1032
#define BATCH 8
#define NHEADS 12
#define HD 64
#define CDIM 768
#define MROWS (BATCH * NSEQ)   // 8256
#define PREFIX 8
#define BQ_ROWS 1152           // padded query rows for bias table (9*128)
#define BK_COLS 1088           // padded key cols for bias table (17*64)

__device__ __forceinline__ unsigned short f2bf_rne(float f) {
    union { float f; uint32_t u; } v; v.f = f;
    uint32_t u = v.u;
    return (unsigned short)((u + 0x7fffu + ((u >> 16) & 1u)) >> 16);
}

__device__ __forceinline__ void gload_lds16(const bf16* g, bf16* l) {
    __builtin_amdgcn_global_load_lds(
        (const __attribute__((address_space(1))) void*)g,
        (__attribute__((address_space(3))) void*)l, 16, 0, 0);
}

__global__ void cast_kernel(const float* __restrict__ src, bf16* __restrict__ dst, int n4) {
    int i = blockIdx.x * blockDim.x + threadIdx.x;
    if (i < n4) {
        float4 f = ((const float4*)src)[i];
        ushort4 o;
        o.x = f2bf_rne(f.x); o.y = f2bf_rne(f.y);
        o.z = f2bf_rne(f.z); o.w = f2bf_rne(f.w);
        ((ushort4*)dst)[i] = o;
    }
}

// Bias table: gauss(q,k) for valid, 0 for prefix rows/cols, -1e30 tail mask.
__global__ void bias_kernel(float* __restrict__ Bias) {
    int i = blockIdx.x * blockDim.x + threadIdx.x;
    if (i >= BQ_ROWS * BK_COLS) return;
    int q = i / BK_COLS, k = i % BK_COLS;
    float v;
    if (k >= NSEQ) v = -1e30f;
    else if (q < PREFIX || q >= NSEQ || k < PREFIX) v = 0.f;
    else {
        int rp = q - PREFIX, cp = k - PREFIX;
        int d1 = (rp >> 5) - (cp >> 5);
        int d2 = (rp & 31) - (cp & 31);
        v = __expf(-0.02f * (float)(d1 * d1 + d2 * d2));
    }
    Bias[i] = v;
}

// NT GEMM, m97-style DMA staging, all address math hoisted out of the K-loop.
// EPI=0: fp32 out. EPI=1: k scaled by sqrt(0.125) -> K[B,H,N,64]; v -> VT[B,H,64,N].
template<int EPI>
__global__ __launch_bounds__(256) void gemm_nt(
    const bf16* __restrict__ A, const bf16* __restrict__ B,
    const float* __restrict__ bias,
    float* __restrict__ Cout, bf16* __restrict__ Kout, bf16* __restrict__ VTout,
    int M, int N, int K)
{
    __shared__ bf16 sA[128 * 32];
    __shared__ bf16 sB[128 * 32];
    const int t = threadIdx.x;
    const int w = t >> 6;
    const int l = t & 63;
    const int quad = l >> 4;
    const int l15 = l & 15;
    const int wy = w >> 1, wx = w & 1;
    const int m0 = blockIdx.y * 128;
    const int n0 = blockIdx.x * 128;
    const int co = (quad ^ ((l15 >> 1) & 3)) * 8;   // swizzled k-chunk (bf16 elems)

    // hoisted staging descriptors: chunk ids t and t+256
    int r0 = t >> 2,          c0 = (t & 3) ^ ((r0 >> 1) & 3);
    int r1 = (t + 256) >> 2,  c1 = ((t + 256) & 3) ^ ((r1 >> 1) & 3);
    int ra0 = m0 + r0; if (ra0 >= M) ra0 = M - 1;
    int ra1 = m0 + r1; if (ra1 >= M) ra1 = M - 1;
    const bf16* gA0 = A + (size_t)ra0 * K + c0 * 8;
    const bf16* gA1 = A + (size_t)ra1 * K + c1 * 8;
    const bf16* gB0 = B + (size_t)(n0 + r0) * K + c0 * 8;
    const bf16* gB1 = B + (size_t)(n0 + r1) * K + c1 * 8;
    bf16* dA0 = &sA[(size_t)(w * 64) * 8];          // wave-uniform DMA bases
    bf16* dA1 = &sA[(size_t)(256 + w * 64) * 8];
    bf16* dB0 = &sB[(size_t)(w * 64) * 8];
    bf16* dB1 = &sB[(size_t)(256 + w * 64) * 8];

    f32x4 acc[4][4] = {};

    for (int k0 = 0; k0 < K; k0 += 32) {
        __syncthreads();
        gload_lds16(gA0, dA0); gload_lds16(gA1, dA1);
        gload_lds16(gB0, dB0); gload_lds16(gB1, dB1);
        gA0 += 32; gA1 += 32; gB0 += 32; gB1 += 32;
        __syncthreads();
        bf16x8 af[4], bq[4];
        #pragma unroll
        for (int mt = 0; mt < 4; ++mt)
            af[mt] = *(const bf16x8*)&sA[(wy*64 + mt*16 + l15) * 32 + co];
        #pragma unroll
        for (int nt = 0; nt < 4; ++nt)
            bq[nt] = *(const bf16x8*)&sB[(wx*64 + nt*16 + l15) * 32 + co];
        #pragma unroll
        for (int mt = 0; mt < 4; ++mt)
            #pragma unroll
            for (int nt = 0; nt < 4; ++nt)
                acc[mt][nt] = __builtin_amdgcn_mfma_f32_16x16x32_bf16(af[mt], bq[nt], acc[mt][nt], 0, 0, 0);
    }

    #pragma unroll
    for (int mt = 0; mt < 4; ++mt) {
        #pragma unroll
        for (int r = 0; r < 4; ++r) {
            int m = m0 + wy*64 + mt*16 + quad*4 + r;
            if (m >= M) continue;
            #pragma unroll
            for (int nt = 0; nt < 4; ++nt) {
                int n = n0 + wx*64 + nt*16 + l15;
                float v = acc[mt][nt][r] + bias[n];
                if (EPI == 0) {
                    Cout[(size_t)m * N + n] = v;
                } else {
                    int b = m / NSEQ, s = m % NSEQ;
                    if (n < CDIM) {
                        int h = n >> 6, d = n & 63;
                        Kout[(((size_t)(b*NHEADS + h))*NSEQ + s)*HD + d] = (bf16)(v * 0.35355339f);
                    } else {
                        int n2 = n - CDIM;
                        int h = n2 >> 6, d = n2 & 63;
                        VTout[(((size_t)(b*NHEADS + h))*HD + d)*NSEQ + s] = (bf16)v;
                    }
                }
            }
        }
    }
}

// Attention, software-pipelined: next tile's K/VT/bias prefetched into regs
// during compute. S^T = K'K'^T + gauss (C-init), P = exp(S), O = PV / rowsum.
// 8 waves x 16 q-rows, K-tile 64. sP XOR-swizzled (granule ^ l15&7).
__global__ __launch_bounds__(512) void attn_kernel(
    const bf16* __restrict__ Kbuf, const bf16* __restrict__ VTbuf,
    const float* __restrict__ Bias, bf16* __restrict__ Hout)
{
    const int bh = blockIdx.y;
    const int b = bh / NHEADS, h = bh % NHEADS;
    const int q0 = blockIdx.x * 128;
    const bf16* Kh  = Kbuf  + (size_t)bh * NSEQ * HD;
    const bf16* VTh = VTbuf + (size_t)bh * HD * NSEQ;

    __shared__ bf16 sK[64][72];
    __shared__ bf16 sVT[64][72];
    __shared__ bf16 sP[128 * 64];
    __shared__ float sL[128];

    const int t = threadIdx.x;
    const int w = t >> 6, l = t & 63, quad = l >> 4, l15 = l & 15;

    // Q fragment in registers (B-operand; 16 query rows per wave)
    bf16x8 qf[2];
    {
        int row = q0 + w*16 + l15;
        if (row > NSEQ - 1) row = NSEQ - 1;
        #pragma unroll
        for (int ks = 0; ks < 2; ++ks)
            qf[ks] = *(const bf16x8*)&Kh[(size_t)row * HD + ks*32 + quad*8];
    }

    const int qg = q0 + w*16 + l15;           // bias row (always < 1152)
    const int srow = t >> 3;
    const int sck  = (t & 7) * 8;
    const int sPr  = (w*16 + l15) * 64;       // this lane's sP row base
    const int sw   = l15 & 7;                 // swizzle key

    f32x4 Oacc[4] = {};
    float ps[4] = {0.f, 0.f, 0.f, 0.f};

    // initial prefetch (tile 0)
    uint4 kv, vv;
    f32x4 bias_pf[4];
    {
        kv = *(const uint4*)&Kh[(size_t)srow * HD + sck];
        vv = *(const uint4*)&VTh[(size_t)srow * NSEQ + sck];
        #pragma unroll
        for (int kt = 0; kt < 4; ++kt)
            bias_pf[kt] = *(const f32x4*)&Bias[(size_t)qg * BK_COLS + kt*16 + quad*4];
    }

    for (int j0 = 0; j0 < NSEQ; j0 += 64) {
        *(uint4*)&sK[srow][sck] = kv;
        *(uint4*)&sVT[srow][sck] = vv;
        f32x4 sacc[4];
        #pragma unroll
        for (int kt = 0; kt < 4; ++kt) sacc[kt] = bias_pf[kt];
        __syncthreads();

        // prefetch next tile (consumed next iteration; latency hidden by compute)
        {
            int jn = j0 + 64; if (jn >= NSEQ) jn = j0;
            int rk = jn + srow; if (rk > NSEQ - 1) rk = NSEQ - 1;
            kv = *(const uint4*)&Kh[(size_t)rk * HD + sck];
            int cs = jn + sck; if (cs > NSEQ - 8) cs = NSEQ - 8;
            vv = *(const uint4*)&VTh[(size_t)srow * NSEQ + cs];
            #pragma unroll
            for (int kt = 0; kt < 4; ++kt)
                bias_pf[kt] = *(const f32x4*)&Bias[(size_t)qg * BK_COLS + jn + kt*16 + quad*4];
        }

        // S^T = K' * Q'^T  (A = keys from LDS, B = query frag in regs)
        #pragma unroll
        for (int ks = 0; ks < 2; ++ks) {
            bf16x8 af[4];
            #pragma unroll
            for (int kt = 0; kt < 4; ++kt)
                af[kt] = *(const bf16x8*)&sK[kt*16 + l15][ks*32 + quad*8];
            #pragma unroll
            for (int kt = 0; kt < 4; ++kt)
                sacc[kt] = __builtin_amdgcn_mfma_f32_16x16x32_bf16(af[kt], qf[ks], sacc[kt], 0, 0, 0);
        }

        // P = exp(S); swizzled b64 store (4 keys/lane)
        #pragma unroll
        for (int kt = 0; kt < 4; ++kt) {
            float p0 = __expf(sacc[kt][0]);
            float p1 = __expf(sacc[kt][1]);
            float p2 = __expf(sacc[kt][2]);
            float p3 = __expf(sacc[kt][3]);
            ps[kt] += (p0 + p1) + (p2 + p3);
            bf16x4 pv = { (bf16)p0, (bf16)p1, (bf16)p2, (bf16)p3 };
            int g = (kt*2 + (quad >> 1)) ^ sw;
            *(bf16x4*)&sP[sPr + g*8 + (quad & 1)*4] = pv;
        }

        // O += P V   (sP rows wave-private; sVT covered by barrier above)
        #pragma unroll
        for (int ks = 0; ks < 2; ++ks) {
            bf16x8 ap, bv[4];
            ap = *(const bf16x8*)&sP[sPr + (((ks*4 + quad) ^ sw) * 8)];
            #pragma unroll
            for (int dt = 0; dt < 4; ++dt)
                bv[dt] = *(const bf16x8*)&sVT[dt*16 + l15][ks*32 + quad*8];
            #pragma unroll
            for (int dt = 0; dt < 4; ++dt)
                Oacc[dt] = __builtin_amdgcn_mfma_f32_16x16x32_bf16(ap, bv[dt], Oacc[dt], 0, 0, 0);
        }
        __syncthreads();
    }

    // row sums: reduce across quads, distribute via LDS
    {
        float s = (ps[0] + ps[1]) + (ps[2] + ps[3]);
        s += __shfl_xor(s, 16, 64);
        s += __shfl_xor(s, 32, 64);
        if (l < 16) sL[w*16 + l] = s;
    }
    __syncthreads();

    #pragma unroll
    for (int r = 0; r < 4; ++r) {
        int g = q0 + w*16 + quad*4 + r;
        if (g >= NSEQ) continue;
        float inv = 1.f / sL[w*16 + quad*4 + r];
        size_t base = ((size_t)(b * NSEQ) + g) * CDIM + h * HD;
        #pragma unroll
        for (int dt = 0; dt < 4; ++dt)
            Hout[base + dt*16 + l15] = (bf16)(Oacc[dt][r] * inv);
    }
}

extern "C" void kernel_launch(void* const* d_in, const int* in_sizes, int n_in,
                              void* d_out, int out_size, void* d_ws, size_t ws_size,
                              hipStream_t stream) {
    const float* x      = (const float*)d_in[0];
    const float* qkv_w  = (const float*)d_in[1];
    const float* qkv_b  = (const float*)d_in[2];
    const float* proj_w = (const float*)d_in[3];
    const float* proj_b = (const float*)d_in[4];
    float* out = (float*)d_out;

    char* ws = (char*)d_ws;
    const size_t XBF_BYTES   = (size_t)MROWS * CDIM * 2;
    const size_t WKV_BYTES   = (size_t)2 * CDIM * CDIM * 2;
    const size_t PW_BYTES    = (size_t)CDIM * CDIM * 2;
    const size_t KBF_BYTES   = (size_t)BATCH * NHEADS * NSEQ * HD * 2;

    bf16* x_bf   = (bf16*)ws;                                     // later reused as hidden
    bf16* wkv_bf = (bf16*)(ws + XBF_BYTES);
    bf16* pw_bf  = (bf16*)(ws + XBF_BYTES + WKV_BYTES);
    bf16* k_bf   = (bf16*)(ws + XBF_BYTES + WKV_BYTES + PW_BYTES);
    bf16* vT_bf  = (bf16*)(ws + XBF_BYTES + WKV_BYTES + PW_BYTES + KBF_BYTES);
    float* bias_t= (float*)(ws + XBF_BYTES + WKV_BYTES + PW_BYTES + KBF_BYTES + KBF_BYTES);

    {
        int n = BQ_ROWS * BK_COLS;
        bias_kernel<<<dim3((n + 255) / 256), dim3(256), 0, stream>>>(bias_t);
    }
    {
        int n4 = MROWS * CDIM / 4;
        cast_kernel<<<dim3((n4 + 255) / 256), dim3(256), 0, stream>>>(x, x_bf, n4);
    }
    {
        int n4 = 2 * CDIM * CDIM / 4;
        cast_kernel<<<dim3((n4 + 255) / 256), dim3(256), 0, stream>>>(qkv_w + (size_t)CDIM * CDIM, wkv_bf, n4);
    }
    {
        int n4 = CDIM * CDIM / 4;
        cast_kernel<<<dim3((n4 + 255) / 256), dim3(256), 0, stream>>>(proj_w, pw_bf, n4);
    }

    // qkv GEMM (k & v only): M=8256, N=1536, K=768
    {
        dim3 grid(1536 / 128, (MROWS + 127) / 128);
        gemm_nt<1><<<grid, dim3(256), 0, stream>>>(x_bf, wkv_bf, qkv_b + CDIM,
                                                   nullptr, k_bf, vT_bf,
                                                   MROWS, 1536, CDIM);
    }

    // attention -> hidden (reuse x_bf buffer)
    {
        dim3 grid((NSEQ + 127) / 128, BATCH * NHEADS);
        attn_kernel<<<grid, dim3(512), 0, stream>>>(k_bf, vT_bf, bias_t, x_bf);
    }

    // proj GEMM: out = hidden @ proj_w^T + proj_b, fp32 out
    {
        dim3 grid(CDIM / 128, (MROWS + 127) / 128);
        gemm_nt<0><<<grid, dim3(256), 0, stream>>>(x_bf, pw_bf, proj_b,
                                                   out, nullptr, nullptr,
                                                   MROWS, CDIM, CDIM);
    }
}